// Round 10
// baseline (253.357 us; speedup 1.0000x reference)
//
#include <hip/hip_runtime.h>
#include <hip/hip_fp16.h>

// NNUE (HalfKA) fused forward pass for MI355X.
// Round 10: r8 structure; k1 register-dieted under the 64-VGPR occupancy
// cliff (packed u16 indices, loop-local biases) + __launch_bounds__(256,8)
// -> 32 waves/CU for latency hiding. Everything else as r8.

#define FEATS 32
#define FTO   1024
#define HH    512
#define ROWS  22528
#define FT_ELEMS  (22528ULL * 1024ULL)     // int8 table bytes = 23,068,672
#define FC0SH_BYTES (8ULL * 8 * 16 * 128 * 2)  // 262,144
#define QSCALE   (6.0f / 127.0f)

__device__ __forceinline__ float clip127(float x) {
    return fminf(fmaxf(x, 0.0f), 127.0f);
}

__device__ __forceinline__ void dec16(const uint4 v, unsigned* acc) {
    acc[0] += __builtin_amdgcn_perm(v.x, v.x, 0x0C010C00u);
    acc[1] += __builtin_amdgcn_perm(v.x, v.x, 0x0C030C02u);
    acc[2] += __builtin_amdgcn_perm(v.y, v.y, 0x0C010C00u);
    acc[3] += __builtin_amdgcn_perm(v.y, v.y, 0x0C030C02u);
    acc[4] += __builtin_amdgcn_perm(v.z, v.z, 0x0C010C00u);
    acc[5] += __builtin_amdgcn_perm(v.z, v.z, 0x0C030C02u);
    acc[6] += __builtin_amdgcn_perm(v.w, v.w, 0x0C010C00u);
    acc[7] += __builtin_amdgcn_perm(v.w, v.w, 0x0C030C02u);
}

__device__ __forceinline__ void quant16(const float4 a, const float4 b,
                                        const float4 c, const float4 d,
                                        unsigned* w) {
    const float inv = 127.0f / 6.0f;
    const float4 vs[4] = {a, b, c, d};
    #pragma unroll
    for (int j = 0; j < 4; ++j) {
        const float4 v = vs[j];
        const unsigned q0 = (unsigned)(__float2int_rn(fminf(fmaxf(v.x * inv, -127.f), 127.f)) + 128);
        const unsigned q1 = (unsigned)(__float2int_rn(fminf(fmaxf(v.y * inv, -127.f), 127.f)) + 128);
        const unsigned q2 = (unsigned)(__float2int_rn(fminf(fmaxf(v.z * inv, -127.f), 127.f)) + 128);
        const unsigned q3 = (unsigned)(__float2int_rn(fminf(fmaxf(v.w * inv, -127.f), 127.f)) + 128);
        w[j] = q0 | (q1 << 8) | (q2 << 16) | (q3 << 24);
    }
}

// ---------------- quantize: fp32 -> biased int8, pairing-aware shards --------
// shard g row layout (128 B): bytes [0,64) = cols [64g, 64g+64),
//                             bytes [64,128) = cols [512+64g, 512+64g+64).
__global__ __launch_bounds__(256) void quant_sh(const float* __restrict__ src,
                                                char* __restrict__ tbl_sh) {
    const int g     = blockIdx.x & 7;
    const int chunk = blockIdx.x >> 3;           // [0, 704)
    const int t     = threadIdx.x;
    const int row   = chunk * 32 + (t >> 3);
    const int c16   = (t & 7) * 16;              // byte offset in shard row
    const int col   = (c16 < 64) ? (64 * g + c16) : (512 + 64 * g + (c16 - 64));
    const float4* s4 = reinterpret_cast<const float4*>(
        src + (size_t)row * FTO + col);
    unsigned w[4];
    quant16(s4[0], s4[1], s4[2], s4[3], w);
    *reinterpret_cast<uint4*>(tbl_sh + (size_t)g * (ROWS * 128)
                              + (size_t)row * 128 + c16) =
        make_uint4(w[0], w[1], w[2], w[3]);
}

// ---------------- quantize row-major (round-5 fallback) ----------------------
__global__ __launch_bounds__(256) void quant_f32_u8(const float4* __restrict__ src,
                                                    uint4* __restrict__ dst,
                                                    unsigned n16) {
    unsigned i = blockIdx.x * 256 + threadIdx.x;
    const unsigned stride = gridDim.x * 256;
    for (; i < n16; i += stride) {
        unsigned w[4];
        quant16(src[4*(size_t)i], src[4*(size_t)i+1], src[4*(size_t)i+2],
                src[4*(size_t)i+3], w);
        dst[i] = make_uint4(w[0], w[1], w[2], w[3]);
    }
}

// ---------------- fc0 weights -> sharded fp16 [g][bk][o][j128] --------------
__global__ __launch_bounds__(256) void cvt_fc0_sh(const float* __restrict__ fc0_w,
                                                  __half* __restrict__ dst) {
    const int idx = blockIdx.x * 256 + threadIdx.x;   // < 131072
    const int j  = idx & 127;
    const int o  = (idx >> 7) & 15;
    const int bk = (idx >> 11) & 7;
    const int g  = idx >> 14;
    const int col = (j < 64) ? (64 * g + j) : (512 + 64 * g + (j - 64));
    dst[idx] = __float2half_rn(fc0_w[((size_t)bk * 16 + o) * FTO + col]);
}

// ---------------- K1: transposed sharded gather + pairwise + fc0 -------------
// Block: shard g = blockIdx&7 (XCD heuristic); 4 waves x 8 samples.
// Lane = samp8*8 + c: owns 16B chunk c of shard row for sample samp8.
// Register diet: indices packed 2-per-reg (u16), biases loaded in-loop.
__global__ __launch_bounds__(256, 8) void k1_fused(
    const int*    __restrict__ w_feats,
    const int*    __restrict__ b_feats,
    const int*    __restrict__ stm,
    const int*    __restrict__ bucket,
    const char*   __restrict__ tbl_sh,
    const __half* __restrict__ fc0_sh,
    const float*  __restrict__ ft_bias,
    float*        __restrict__ acc_f,
    int nB)
{
    const int tid   = threadIdx.x;
    const int lane  = tid & 63;
    const int wv    = tid >> 6;
    const int g     = blockIdx.x & 7;
    const int slot  = (blockIdx.x >> 3) * 4 + wv;
    const int samp8 = lane >> 3;
    const int c     = lane & 7;
    const int s0    = slot * 8 + samp8;
    const int s     = (s0 < nB) ? s0 : (nB - 1);
    const size_t gbase = (size_t)g * (ROWS * 128ULL);
    const char* __restrict__ tbc = tbl_sh + gbase + c * 16;

    // ---- packed indices: pk[j] = pos(lo) | pos(hi)<<16 (rows < 2^15) ----
    int pk[4];
    {
        const int* __restrict__ wf = w_feats + (size_t)s * FEATS;
        const int* __restrict__ bf = b_feats + (size_t)s * FEATS;
        pk[0] = wf[c]      | (wf[c + 8]  << 16);
        pk[1] = wf[c + 16] | (wf[c + 24] << 16);
        pk[2] = bf[c]      | (bf[c + 8]  << 16);
        pk[3] = bf[c + 16] | (bf[c + 24] << 16);
    }

    unsigned accW[8] = {0,0,0,0,0,0,0,0};
    unsigned accB[8] = {0,0,0,0,0,0,0,0};
    const int grpbase = lane & 56;

    // ---- gather-sum: 8 batches of 8 row-chunk loads (compiler pipelines) ----
    #pragma unroll
    for (int t = 0; t < 8; ++t) {
        uint4 buf[8];
        #pragma unroll
        for (int u = 0; u < 8; ++u) {
            const int pr  = __shfl(pk[t >> 1], grpbase + u);
            const int row = (t & 1) ? (pr >> 16) : (pr & 0xFFFF);
            buf[u] = *reinterpret_cast<const uint4*>(tbc + (size_t)row * 128);
        }
        unsigned* acc = (t < 4) ? accW : accB;
        #pragma unroll
        for (int u = 0; u < 8; ++u) dec16(buf[u], acc);
    }

    const int st = stm[s];
    const int bk = bucket[s];

    // ---- stm select + pairing exchange with lane c^4 ----
    unsigned A[8], P[8];
    #pragma unroll
    for (int i = 0; i < 8; ++i) {
        const unsigned sS = st ? accB[i] : accW[i];
        const unsigned sO = st ? accW[i] : accB[i];
        A[i] = (c < 4) ? sS : sO;
        P[i] = __shfl_xor((c < 4) ? sO : sS, 4);
    }

    // ---- decode + pairwise clip-mult (biases loaded in-loop, L1-hot) ----
    const float qs   = QSCALE;
    const float qoff = -4096.0f * QSCALE;   // 32 rows * 128 bias
    const int cb       = 16 * (c & 3);
    const int lo_base  = 64 * g + cb;
    const int hi_base  = 512 + 64 * g + cb;
    const int own_base = (c < 4) ? lo_base : hi_base;
    const int par_base = (c < 4) ? hi_base : lo_base;

    float ftv[16];
    #pragma unroll
    for (int i2 = 0; i2 < 4; ++i2) {
        const float4 vo = *reinterpret_cast<const float4*>(ft_bias + own_base + 4 * i2);
        const float4 vp = *reinterpret_cast<const float4*>(ft_bias + par_base + 4 * i2);
        const unsigned a0 = A[2 * i2], a1 = A[2 * i2 + 1];
        const unsigned p0 = P[2 * i2], p1 = P[2 * i2 + 1];
        const float o0v = (float)(a0 & 0xFFFFu) * qs + (vo.x + qoff);
        const float o1v = (float)(a0 >> 16)     * qs + (vo.y + qoff);
        const float o2v = (float)(a1 & 0xFFFFu) * qs + (vo.z + qoff);
        const float o3v = (float)(a1 >> 16)     * qs + (vo.w + qoff);
        const float q0v = (float)(p0 & 0xFFFFu) * qs + (vp.x + qoff);
        const float q1v = (float)(p0 >> 16)     * qs + (vp.y + qoff);
        const float q2v = (float)(p1 & 0xFFFFu) * qs + (vp.z + qoff);
        const float q3v = (float)(p1 >> 16)     * qs + (vp.w + qoff);
        ftv[4*i2+0] = clip127(o0v) * clip127(q0v) * (1.0f/128.0f);
        ftv[4*i2+1] = clip127(o1v) * clip127(q1v) * (1.0f/128.0f);
        ftv[4*i2+2] = clip127(o2v) * clip127(q2v) * (1.0f/128.0f);
        ftv[4*i2+3] = clip127(o3v) * clip127(q3v) * (1.0f/128.0f);
    }

    // ---- fc0 partials from L1-hot global weights (32 KB/shard) ----
    const __half* __restrict__ wbase =
        fc0_sh + ((size_t)g * 8 + bk) * (16 * 128) + 16 * c;
    float p[16];
    #pragma unroll
    for (int o = 0; o < 16; ++o) {
        const __half2* w2 = reinterpret_cast<const __half2*>(wbase + o * 128);
        float pv = 0.0f;
        #pragma unroll
        for (int j = 0; j < 8; ++j) {
            const float2 f = __half22float2(w2[j]);
            pv += ftv[2*j] * f.x + ftv[2*j+1] * f.y;
        }
        p[o] = pv;
    }

    // ---- 14-shuffle keep/send tree: 16 partials over 8 lanes -> 2/lane ----
    float q8[8];
    {
        const bool hi = (c & 1) != 0;
        #pragma unroll
        for (int o = 0; o < 8; ++o) {
            const float send = hi ? p[o] : p[o + 8];
            const float keep = hi ? p[o + 8] : p[o];
            q8[o] = keep + __shfl_xor(send, 1);
        }
    }
    float q4[4];
    {
        const bool hi = (c & 2) != 0;
        #pragma unroll
        for (int o = 0; o < 4; ++o) {
            const float send = hi ? q8[o] : q8[o + 4];
            const float keep = hi ? q8[o + 4] : q8[o];
            q4[o] = keep + __shfl_xor(send, 2);
        }
    }
    float q2[2];
    {
        const bool hi = (c & 4) != 0;
        #pragma unroll
        for (int o = 0; o < 2; ++o) {
            const float send = hi ? q4[o] : q4[o + 2];
            const float keep = hi ? q4[o + 2] : q4[o];
            q2[o] = keep + __shfl_xor(send, 4);
        }
    }
    const int m = ((c & 1) << 2) | (c & 2) | (c >> 2);

    if (s0 < nB) {
        float2* dst = reinterpret_cast<float2*>(acc_f + ((size_t)s * 8 + g) * 16);
        dst[m] = make_float2(q2[0], q2[1]);
    }
}

// ---------------- K2: tiny finisher ----------------
__global__ __launch_bounds__(256, 4) void k2_final(
    const int*   __restrict__ w_feats,
    const int*   __restrict__ b_feats,
    const int*   __restrict__ stm,
    const int*   __restrict__ bucket,
    const float* __restrict__ acc_f,
    const float* __restrict__ psqt_w,
    const float* __restrict__ fc0_b,
    const float* __restrict__ fc1_w,
    const float* __restrict__ fc1_b,
    const float* __restrict__ fc2_w,
    const float* __restrict__ fc2_b,
    float*       __restrict__ out,
    int nB)
{
    const int tid  = threadIdx.x;
    const int lane = tid & 63;
    const int wv   = tid >> 6;
    const int s    = blockIdx.x * 4 + wv;
    if (s >= nB) return;

    const int* __restrict__ wf = w_feats + s * FEATS;
    const int* __restrict__ bf = b_feats + s * FEATS;

    // ---- psqt gather ----
    const int pj = lane & 7, rg = lane >> 3;
    float psw = 0.0f, psb = 0.0f;
    #pragma unroll
    for (int t = 0; t < 4; ++t) psw += psqt_w[(size_t)wf[t * 8 + rg] * 8 + pj];
    #pragma unroll
    for (int t = 0; t < 4; ++t) psb += psqt_w[(size_t)bf[t * 8 + rg] * 8 + pj];
    psw += __shfl_xor(psw, 8);  psb += __shfl_xor(psb, 8);
    psw += __shfl_xor(psw, 16); psb += __shfl_xor(psb, 16);
    psw += __shfl_xor(psw, 32); psb += __shfl_xor(psb, 32);

    const int st = stm[s];
    const int bk = bucket[s];

    // ---- o0: sum 8 shard partials; lane holds o = lane&15 ----
    const float r0 = acc_f[(size_t)s * 128 + lane];        // g = lane>>4
    const float r1 = acc_f[(size_t)s * 128 + 64 + lane];   // g = 4 + (lane>>4)
    float v = r0 + r1;
    v += __shfl_xor(v, 16);
    v += __shfl_xor(v, 32);
    v += fc0_b[bk * 16 + (lane & 15)];

    // ---- fc1 on lanes 0..31 ----
    float t2 = 0.0f;
    if (lane < 32) {
        const float* __restrict__ w1 = fc1_w + ((size_t)bk * 32 + lane) * 32;
        float o1 = fc1_b[bk * 32 + lane];
        #pragma unroll
        for (int i = 0; i < 15; ++i) {
            const float o0i = __shfl(v, i);
            const float sq  = clip127(o0i * o0i * (1.0f/524288.0f));
            const float rl  = clip127(o0i * (1.0f/64.0f));
            o1 += sq * w1[i] + rl * w1[15 + i];
        }
        const float ac1 = clip127(o1 * (1.0f/64.0f));
        t2 = ac1 * fc2_w[bk * 32 + lane];
    } else {
        (void)__shfl(v, 0);
    }
    t2 += __shfl_xor(t2, 1);
    t2 += __shfl_xor(t2, 2);
    t2 += __shfl_xor(t2, 4);
    t2 += __shfl_xor(t2, 8);
    t2 += __shfl_xor(t2, 16);
    t2 += __shfl_xor(t2, 32);

    const float skip = __shfl(v, 15) * (9600.0f / 8128.0f);
    const float pwbk = __shfl(psw, bk);
    const float pbbk = __shfl(psb, bk);

    if (lane == 0) {
        const float scalar = t2 + fc2_b[bk];
        const float p_stm  = st ? pbbk : pwbk;
        const float p_opp  = st ? pwbk : pbbk;
        out[s] = ((p_stm - p_opp) * 0.5f + scalar + skip) * (1.0f / 16.0f);
    }
}

// ---------------- round-5 fallback: wave-per-sample, row-major int8 ----------
__global__ __launch_bounds__(256, 4) void nnue_wave_q8(
    const int*   __restrict__ w_feats,
    const int*   __restrict__ b_feats,
    const int*   __restrict__ stm,
    const int*   __restrict__ bucket,
    const char*  __restrict__ tb,
    const float* __restrict__ ft_bias,
    const float* __restrict__ psqt_w,
    const float* __restrict__ fc0_w,
    const float* __restrict__ fc0_b,
    const float* __restrict__ fc1_w,
    const float* __restrict__ fc1_b,
    const float* __restrict__ fc2_w,
    const float* __restrict__ fc2_b,
    float*       __restrict__ out,
    int nB)
{
    const int tid  = threadIdx.x;
    const int lane = tid & 63;
    const int wv   = tid >> 6;
    const int s    = blockIdx.x * 4 + wv;
    if (s >= nB) return;

    const int* __restrict__ wf = w_feats + s * FEATS;
    const int* __restrict__ bf = b_feats + s * FEATS;
    const size_t loff = (size_t)(lane * 16);

    unsigned accW[8] = {0,0,0,0,0,0,0,0};
    unsigned accB[8] = {0,0,0,0,0,0,0,0};
    {
        uint4 buf[16];
        #pragma unroll
        for (int batch = 0; batch < 4; ++batch) {
            const int* fp = ((batch < 2) ? wf : bf) + (batch & 1) * 16;
            #pragma unroll
            for (int k = 0; k < 16; ++k)
                buf[k] = *reinterpret_cast<const uint4*>(tb + ((size_t)fp[k] << 10) + loff);
            unsigned* acc = (batch < 2) ? accW : accB;
            #pragma unroll
            for (int k = 0; k < 16; ++k) dec16(buf[k], acc);
        }
    }

    const int pj = lane & 7, rg = lane >> 3;
    float psw = 0.0f, psb = 0.0f;
    #pragma unroll
    for (int t = 0; t < 4; ++t) psw += psqt_w[(size_t)wf[t * 8 + rg] * 8 + pj];
    #pragma unroll
    for (int t = 0; t < 4; ++t) psb += psqt_w[(size_t)bf[t * 8 + rg] * 8 + pj];
    psw += __shfl_xor(psw, 8);  psb += __shfl_xor(psb, 8);
    psw += __shfl_xor(psw, 16); psb += __shfl_xor(psb, 16);
    psw += __shfl_xor(psw, 32); psb += __shfl_xor(psb, 32);

    const int st = stm[s];
    unsigned as_[8], ao_[8];
    #pragma unroll
    for (int i = 0; i < 8; ++i) {
        as_[i] = st ? accB[i] : accW[i];
        ao_[i] = st ? accW[i] : accB[i];
    }
    unsigned asw[8], aosw[8];
    #pragma unroll
    for (int i = 0; i < 8; ++i) {
        asw[i]  = __shfl_xor(as_[i], 32);
        aosw[i] = __shfl_xor(ao_[i], 32);
    }
    const bool hiG  = (lane >= 32);
    const int cbase = (lane & 31) * 16;

    const float qs   = QSCALE;
    const float qoff = -4096.0f * QSCALE;
    float ftv[16];
    #pragma unroll
    for (int i2 = 0; i2 < 8; ++i2) {
        const unsigned lo = hiG ? aosw[i2] : as_[i2];
        const unsigned hi = hiG ? ao_[i2]  : asw[i2];
        const float bl0 = ft_bias[cbase + 2 * i2];
        const float bl1 = ft_bias[cbase + 2 * i2 + 1];
        const float bh0 = ft_bias[cbase + HH + 2 * i2];
        const float bh1 = ft_bias[cbase + HH + 2 * i2 + 1];
        const float a0 = (float)(lo & 0xFFFFu) * qs + (bl0 + qoff);
        const float a1 = (float)(lo >> 16)     * qs + (bl1 + qoff);
        const float h0 = (float)(hi & 0xFFFFu) * qs + (bh0 + qoff);
        const float h1 = (float)(hi >> 16)     * qs + (bh1 + qoff);
        ftv[2 * i2]     = clip127(a0) * clip127(h0) * (1.0f / 128.0f);
        ftv[2 * i2 + 1] = clip127(a1) * clip127(h1) * (1.0f / 128.0f);
    }

    const int bk = bucket[s];
    const float* __restrict__ w0 = fc0_w + (size_t)bk * 16 * FTO + 16 * lane;
    float o0[16];
    #pragma unroll
    for (int o = 0; o < 16; ++o) {
        const float4* wr = reinterpret_cast<const float4*>(w0 + o * FTO);
        float pv = 0.0f;
        #pragma unroll
        for (int q = 0; q < 4; ++q) {
            const float4 w = wr[q];
            pv += ftv[4*q] * w.x + ftv[4*q+1] * w.y + ftv[4*q+2] * w.z + ftv[4*q+3] * w.w;
        }
        pv += __shfl_xor(pv, 1);
        pv += __shfl_xor(pv, 2);
        pv += __shfl_xor(pv, 4);
        pv += __shfl_xor(pv, 8);
        pv += __shfl_xor(pv, 16);
        pv += __shfl_xor(pv, 32);
        o0[o] = pv + fc0_b[bk * 16 + o];
    }

    float v = 0.0f;
    if (lane < 32) {
        const float* __restrict__ w1 = fc1_w + ((size_t)bk * 32 + lane) * 32;
        float o1 = fc1_b[bk * 32 + lane];
        #pragma unroll
        for (int i = 0; i < 15; ++i) {
            const float o0i = o0[i];
            const float sq  = clip127(o0i * o0i * (1.0f/524288.0f));
            const float rl  = clip127(o0i * (1.0f/64.0f));
            o1 += sq * w1[i] + rl * w1[15 + i];
        }
        const float ac1 = clip127(o1 * (1.0f/64.0f));
        v = ac1 * fc2_w[bk * 32 + lane];
    }
    v += __shfl_xor(v, 1);
    v += __shfl_xor(v, 2);
    v += __shfl_xor(v, 4);
    v += __shfl_xor(v, 8);
    v += __shfl_xor(v, 16);
    v += __shfl_xor(v, 32);

    const float pwbk = __shfl(psw, bk);
    const float pbbk = __shfl(psb, bk);

    if (lane == 0) {
        const float scalar = v + fc2_b[bk];
        const float skip   = o0[15] * (9600.0f / 8128.0f);
        const float p_stm  = st ? pbbk : pwbk;
        const float p_opp  = st ? pwbk : pbbk;
        out[s] = ((p_stm - p_opp) * 0.5f + scalar + skip) * (1.0f / 16.0f);
    }
}

extern "C" void kernel_launch(void* const* d_in, const int* in_sizes, int n_in,
                              void* d_out, int out_size, void* d_ws, size_t ws_size,
                              hipStream_t stream) {
    const int*   w_feats = (const int*)  d_in[0];
    const int*   b_feats = (const int*)  d_in[2];
    const int*   stm     = (const int*)  d_in[4];
    const int*   bucket  = (const int*)  d_in[5];
    const float* ft_w    = (const float*)d_in[6];
    const float* ft_bias = (const float*)d_in[7];
    const float* psqt_w  = (const float*)d_in[8];
    const float* fc0_w   = (const float*)d_in[9];
    const float* fc0_b   = (const float*)d_in[10];
    const float* fc1_w   = (const float*)d_in[11];
    const float* fc1_b   = (const float*)d_in[12];
    const float* fc2_w   = (const float*)d_in[13];
    const float* fc2_b   = (const float*)d_in[14];
    float* out = (float*)d_out;

    const int nB = in_sizes[4];

    const size_t accf_bytes = (size_t)nB * 8 * 16 * 4;       // 512 B/sample
    const size_t need_shard = FT_ELEMS + accf_bytes + FC0SH_BYTES;

    if (ws_size >= need_shard) {
        char*   tbl_sh = (char*)d_ws;
        float*  acc_f  = (float*)((char*)d_ws + FT_ELEMS);
        __half* fc0sh  = (__half*)((char*)d_ws + FT_ELEMS + accf_bytes);

        quant_sh<<<8 * (ROWS / 32), 256, 0, stream>>>(ft_w, tbl_sh);
        cvt_fc0_sh<<<131072 / 256, 256, 0, stream>>>(fc0_w, fc0sh);
        k1_fused<<<8 * ((nB + 31) / 32), 256, 0, stream>>>(
            w_feats, b_feats, stm, bucket, tbl_sh, fc0sh, ft_bias, acc_f, nB);
        k2_final<<<(nB + 3) / 4, 256, 0, stream>>>(
            w_feats, b_feats, stm, bucket, acc_f, psqt_w,
            fc0_b, fc1_w, fc1_b, fc2_w, fc2_b, out, nB);
    } else if (ws_size >= FT_ELEMS) {
        const unsigned n16 = (unsigned)(FT_ELEMS / 16);
        quant_f32_u8<<<2048, 256, 0, stream>>>((const float4*)ft_w, (uint4*)d_ws, n16);
        nnue_wave_q8<<<(nB + 3) / 4, 256, 0, stream>>>(
            w_feats, b_feats, stm, bucket, (const char*)d_ws, ft_bias, psqt_w,
            fc0_w, fc0_b, fc1_w, fc1_b, fc2_w, fc2_b, out, nB);
    }
}

// Round 11
// 66.865 us; speedup vs baseline: 3.7891x; 3.7891x over previous
//
#include <hip/hip_runtime.h>
#include <hip/hip_fp16.h>

// NNUE (HalfKA) fused forward pass for MI355X.
// Round 11: revert to round-8 structure (proven 68.6 us). Single prep kernel
// (quant + fc0 cvt fused). k1: transposed sharded gather, natural regalloc
// (launch_bounds(256,4), ~56 VGPR, no LDS, no manual pipelining).
// Lessons: r9 manual ping-pong = neutral-negative (compiler already
// pipelines); r10 launch_bounds(256,8) = scratch-spill disaster.

#define FEATS 32
#define FTO   1024
#define HH    512
#define ROWS  22528
#define FT_ELEMS  (22528ULL * 1024ULL)     // int8 table bytes = 23,068,672
#define FC0SH_BYTES (8ULL * 8 * 16 * 128 * 2)  // 262,144
#define QSCALE   (6.0f / 127.0f)
#define QUANT_BLOCKS (8 * (ROWS / 32))     // 5632
#define CVT_BLOCKS   512                   // 131072 / 256

__device__ __forceinline__ float clip127(float x) {
    return fminf(fmaxf(x, 0.0f), 127.0f);
}

__device__ __forceinline__ void dec16(const uint4 v, unsigned* acc) {
    acc[0] += __builtin_amdgcn_perm(v.x, v.x, 0x0C010C00u);
    acc[1] += __builtin_amdgcn_perm(v.x, v.x, 0x0C030C02u);
    acc[2] += __builtin_amdgcn_perm(v.y, v.y, 0x0C010C00u);
    acc[3] += __builtin_amdgcn_perm(v.y, v.y, 0x0C030C02u);
    acc[4] += __builtin_amdgcn_perm(v.z, v.z, 0x0C010C00u);
    acc[5] += __builtin_amdgcn_perm(v.z, v.z, 0x0C030C02u);
    acc[6] += __builtin_amdgcn_perm(v.w, v.w, 0x0C010C00u);
    acc[7] += __builtin_amdgcn_perm(v.w, v.w, 0x0C030C02u);
}

__device__ __forceinline__ void quant16(const float4 a, const float4 b,
                                        const float4 c, const float4 d,
                                        unsigned* w) {
    const float inv = 127.0f / 6.0f;
    const float4 vs[4] = {a, b, c, d};
    #pragma unroll
    for (int j = 0; j < 4; ++j) {
        const float4 v = vs[j];
        const unsigned q0 = (unsigned)(__float2int_rn(fminf(fmaxf(v.x * inv, -127.f), 127.f)) + 128);
        const unsigned q1 = (unsigned)(__float2int_rn(fminf(fmaxf(v.y * inv, -127.f), 127.f)) + 128);
        const unsigned q2 = (unsigned)(__float2int_rn(fminf(fmaxf(v.z * inv, -127.f), 127.f)) + 128);
        const unsigned q3 = (unsigned)(__float2int_rn(fminf(fmaxf(v.w * inv, -127.f), 127.f)) + 128);
        w[j] = q0 | (q1 << 8) | (q2 << 16) | (q3 << 24);
    }
}

// ---------------- prep: table quant (sharded) + fc0 fp16 cvt, one kernel -----
// Blocks [0, 5632): quantize ft_w into pairing-aware shards.
//   shard g row layout (128 B): [0,64)=cols [64g,64g+64),
//                               [64,128)=cols [512+64g,512+64g+64).
// Blocks [5632, 6144): convert fc0_w into sharded fp16 [g][bk][o][j128].
__global__ __launch_bounds__(256) void prep_all(const float* __restrict__ ft_w,
                                                const float* __restrict__ fc0_w,
                                                char* __restrict__ tbl_sh,
                                                __half* __restrict__ fc0h) {
    const int cb = (int)blockIdx.x - QUANT_BLOCKS;
    if (cb < 0) {
        const int g     = blockIdx.x & 7;
        const int chunk = blockIdx.x >> 3;           // [0, 704)
        const int t     = threadIdx.x;
        const int row   = chunk * 32 + (t >> 3);
        const int c16   = (t & 7) * 16;              // byte offset in shard row
        const int col   = (c16 < 64) ? (64 * g + c16) : (512 + 64 * g + (c16 - 64));
        const float4* s4 = reinterpret_cast<const float4*>(
            ft_w + (size_t)row * FTO + col);
        unsigned w[4];
        quant16(s4[0], s4[1], s4[2], s4[3], w);
        *reinterpret_cast<uint4*>(tbl_sh + (size_t)g * (ROWS * 128)
                                  + (size_t)row * 128 + c16) =
            make_uint4(w[0], w[1], w[2], w[3]);
    } else {
        const int idx = cb * 256 + threadIdx.x;      // < 131072
        const int j  = idx & 127;
        const int o  = (idx >> 7) & 15;
        const int bk = (idx >> 11) & 7;
        const int g  = idx >> 14;
        const int col = (j < 64) ? (64 * g + j) : (512 + 64 * g + (j - 64));
        fc0h[idx] = __float2half_rn(fc0_w[((size_t)bk * 16 + o) * FTO + col]);
    }
}

// ---------------- quantize row-major (round-5 fallback) ----------------------
__global__ __launch_bounds__(256) void quant_f32_u8(const float4* __restrict__ src,
                                                    uint4* __restrict__ dst,
                                                    unsigned n16) {
    unsigned i = blockIdx.x * 256 + threadIdx.x;
    const unsigned stride = gridDim.x * 256;
    for (; i < n16; i += stride) {
        unsigned w[4];
        quant16(src[4*(size_t)i], src[4*(size_t)i+1], src[4*(size_t)i+2],
                src[4*(size_t)i+3], w);
        dst[i] = make_uint4(w[0], w[1], w[2], w[3]);
    }
}

// ---------------- K1: transposed sharded gather + pairwise + fc0 -------------
// Block: shard g = blockIdx&7 (XCD heuristic); 4 waves x 8 samples.
// Lane = samp8*8 + c: owns 16B chunk c of shard row for sample samp8.
// Accumulates over all 64 feature rows (no cross-lane reduce), pairs with
// lane c^4, computes fc0 partials, 14-shuffle tree -> out pair {2m,2m+1}.
__global__ __launch_bounds__(256, 4) void k1_fused(
    const int*    __restrict__ w_feats,
    const int*    __restrict__ b_feats,
    const int*    __restrict__ stm,
    const int*    __restrict__ bucket,
    const char*   __restrict__ tbl_sh,
    const __half* __restrict__ fc0_sh,
    const float*  __restrict__ ft_bias,
    float*        __restrict__ acc_f,
    int nB)
{
    const int tid   = threadIdx.x;
    const int lane  = tid & 63;
    const int wv    = tid >> 6;
    const int g     = blockIdx.x & 7;
    const int slot  = (blockIdx.x >> 3) * 4 + wv;
    const int samp8 = lane >> 3;
    const int c     = lane & 7;
    const int s0    = slot * 8 + samp8;
    const int s     = (s0 < nB) ? s0 : (nB - 1);
    const size_t gbase = (size_t)g * (ROWS * 128ULL);
    const char* __restrict__ tbc = tbl_sh + gbase + c * 16;

    // ---- preload indices: lane holds positions c+8t of its sample ----
    int il[8];
    {
        const int* __restrict__ wf = w_feats + (size_t)s * FEATS;
        const int* __restrict__ bf = b_feats + (size_t)s * FEATS;
        #pragma unroll
        for (int t = 0; t < 4; ++t) il[t]     = wf[c + 8 * t];
        #pragma unroll
        for (int t = 0; t < 4; ++t) il[4 + t] = bf[c + 8 * t];
    }

    // ---- gather-sum: 8 batches of 8 row-chunk loads ----
    unsigned accW[8] = {0,0,0,0,0,0,0,0};
    unsigned accB[8] = {0,0,0,0,0,0,0,0};
    const int grpbase = lane & 56;
    #pragma unroll
    for (int t = 0; t < 8; ++t) {
        uint4 buf[8];
        #pragma unroll
        for (int u = 0; u < 8; ++u) {
            const int row = __shfl(il[t], grpbase + u);
            buf[u] = *reinterpret_cast<const uint4*>(tbc + (size_t)row * 128);
        }
        unsigned* acc = (t < 4) ? accW : accB;
        #pragma unroll
        for (int u = 0; u < 8; ++u) dec16(buf[u], acc);
    }

    // ---- biases to registers (fixed per lane), qoff folded ----
    const float qs   = QSCALE;
    const float qoff = -4096.0f * QSCALE;   // 32 rows * 128 bias
    const int cb       = 16 * (c & 3);
    const int lo_base  = 64 * g + cb;
    const int hi_base  = 512 + 64 * g + cb;
    const int own_base = (c < 4) ? lo_base : hi_base;
    const int par_base = (c < 4) ? hi_base : lo_base;
    float bo[16], bp[16];
    #pragma unroll
    for (int i = 0; i < 4; ++i) {
        const float4 vo = *reinterpret_cast<const float4*>(ft_bias + own_base + 4 * i);
        const float4 vp = *reinterpret_cast<const float4*>(ft_bias + par_base + 4 * i);
        bo[4*i+0] = vo.x + qoff; bo[4*i+1] = vo.y + qoff;
        bo[4*i+2] = vo.z + qoff; bo[4*i+3] = vo.w + qoff;
        bp[4*i+0] = vp.x + qoff; bp[4*i+1] = vp.y + qoff;
        bp[4*i+2] = vp.z + qoff; bp[4*i+3] = vp.w + qoff;
    }

    const int st = stm[s];
    const int bk = bucket[s];

    // ---- stm select + pairing exchange with lane c^4 ----
    unsigned A[8], P[8];
    #pragma unroll
    for (int i = 0; i < 8; ++i) {
        const unsigned sS = st ? accB[i] : accW[i];
        const unsigned sO = st ? accW[i] : accB[i];
        A[i] = (c < 4) ? sS : sO;
        P[i] = __shfl_xor((c < 4) ? sO : sS, 4);
    }

    // ---- decode + pairwise clip-mult -> 16 ft values ----
    float ftv[16];
    #pragma unroll
    for (int i = 0; i < 8; ++i) {
        const float vo0 = (float)(A[i] & 0xFFFFu) * qs + bo[2*i];
        const float vo1 = (float)(A[i] >> 16)     * qs + bo[2*i+1];
        const float vp0 = (float)(P[i] & 0xFFFFu) * qs + bp[2*i];
        const float vp1 = (float)(P[i] >> 16)     * qs + bp[2*i+1];
        ftv[2*i]   = clip127(vo0) * clip127(vp0) * (1.0f/128.0f);
        ftv[2*i+1] = clip127(vo1) * clip127(vp1) * (1.0f/128.0f);
    }

    // ---- fc0 partials from L1-hot global weights (32 KB/shard) ----
    const __half* __restrict__ wbase =
        fc0_sh + ((size_t)g * 8 + bk) * (16 * 128) + 16 * c;
    float p[16];
    #pragma unroll
    for (int o = 0; o < 16; ++o) {
        const __half2* w2 = reinterpret_cast<const __half2*>(wbase + o * 128);
        float pv = 0.0f;
        #pragma unroll
        for (int j = 0; j < 8; ++j) {
            const float2 f = __half22float2(w2[j]);
            pv += ftv[2*j] * f.x + ftv[2*j+1] * f.y;
        }
        p[o] = pv;
    }

    // ---- 14-shuffle keep/send tree: 16 partials over 8 lanes -> 2/lane ----
    float q8[8];
    {
        const bool hi = (c & 1) != 0;
        #pragma unroll
        for (int o = 0; o < 8; ++o) {
            const float send = hi ? p[o] : p[o + 8];
            const float keep = hi ? p[o + 8] : p[o];
            q8[o] = keep + __shfl_xor(send, 1);
        }
    }
    float q4[4];
    {
        const bool hi = (c & 2) != 0;
        #pragma unroll
        for (int o = 0; o < 4; ++o) {
            const float send = hi ? q8[o] : q8[o + 4];
            const float keep = hi ? q8[o + 4] : q8[o];
            q4[o] = keep + __shfl_xor(send, 2);
        }
    }
    float q2[2];
    {
        const bool hi = (c & 4) != 0;
        #pragma unroll
        for (int o = 0; o < 2; ++o) {
            const float send = hi ? q4[o] : q4[o + 2];
            const float keep = hi ? q4[o + 2] : q4[o];
            q2[o] = keep + __shfl_xor(send, 4);
        }
    }
    // lane c holds outs {2m, 2m+1}, m = bit-reversed c (3 bits)
    const int m = ((c & 1) << 2) | (c & 2) | (c >> 2);

    if (s0 < nB) {
        float2* dst = reinterpret_cast<float2*>(acc_f + ((size_t)s * 8 + g) * 16);
        dst[m] = make_float2(q2[0], q2[1]);
    }
}

// ---------------- K2: tiny finisher ----------------
__global__ __launch_bounds__(256, 4) void k2_final(
    const int*   __restrict__ w_feats,
    const int*   __restrict__ b_feats,
    const int*   __restrict__ stm,
    const int*   __restrict__ bucket,
    const float* __restrict__ acc_f,
    const float* __restrict__ psqt_w,
    const float* __restrict__ fc0_b,
    const float* __restrict__ fc1_w,
    const float* __restrict__ fc1_b,
    const float* __restrict__ fc2_w,
    const float* __restrict__ fc2_b,
    float*       __restrict__ out,
    int nB)
{
    const int tid  = threadIdx.x;
    const int lane = tid & 63;
    const int wv   = tid >> 6;
    const int s    = blockIdx.x * 4 + wv;
    if (s >= nB) return;

    const int* __restrict__ wf = w_feats + s * FEATS;
    const int* __restrict__ bf = b_feats + s * FEATS;

    // ---- psqt gather ----
    const int pj = lane & 7, rg = lane >> 3;
    float psw = 0.0f, psb = 0.0f;
    #pragma unroll
    for (int t = 0; t < 4; ++t) psw += psqt_w[(size_t)wf[t * 8 + rg] * 8 + pj];
    #pragma unroll
    for (int t = 0; t < 4; ++t) psb += psqt_w[(size_t)bf[t * 8 + rg] * 8 + pj];
    psw += __shfl_xor(psw, 8);  psb += __shfl_xor(psb, 8);
    psw += __shfl_xor(psw, 16); psb += __shfl_xor(psb, 16);
    psw += __shfl_xor(psw, 32); psb += __shfl_xor(psb, 32);

    const int st = stm[s];
    const int bk = bucket[s];

    // ---- o0: sum 8 shard partials; lane holds o = lane&15 ----
    const float r0 = acc_f[(size_t)s * 128 + lane];        // g = lane>>4
    const float r1 = acc_f[(size_t)s * 128 + 64 + lane];   // g = 4 + (lane>>4)
    float v = r0 + r1;
    v += __shfl_xor(v, 16);
    v += __shfl_xor(v, 32);
    v += fc0_b[bk * 16 + (lane & 15)];

    // ---- fc1 on lanes 0..31 ----
    float t2 = 0.0f;
    if (lane < 32) {
        const float* __restrict__ w1 = fc1_w + ((size_t)bk * 32 + lane) * 32;
        float o1 = fc1_b[bk * 32 + lane];
        #pragma unroll
        for (int i = 0; i < 15; ++i) {
            const float o0i = __shfl(v, i);
            const float sq  = clip127(o0i * o0i * (1.0f/524288.0f));
            const float rl  = clip127(o0i * (1.0f/64.0f));
            o1 += sq * w1[i] + rl * w1[15 + i];
        }
        const float ac1 = clip127(o1 * (1.0f/64.0f));
        t2 = ac1 * fc2_w[bk * 32 + lane];
    } else {
        (void)__shfl(v, 0);
    }
    t2 += __shfl_xor(t2, 1);
    t2 += __shfl_xor(t2, 2);
    t2 += __shfl_xor(t2, 4);
    t2 += __shfl_xor(t2, 8);
    t2 += __shfl_xor(t2, 16);
    t2 += __shfl_xor(t2, 32);

    const float skip = __shfl(v, 15) * (9600.0f / 8128.0f);
    const float pwbk = __shfl(psw, bk);
    const float pbbk = __shfl(psb, bk);

    if (lane == 0) {
        const float scalar = t2 + fc2_b[bk];
        const float p_stm  = st ? pbbk : pwbk;
        const float p_opp  = st ? pwbk : pbbk;
        out[s] = ((p_stm - p_opp) * 0.5f + scalar + skip) * (1.0f / 16.0f);
    }
}

// ---------------- round-5 fallback: wave-per-sample, row-major int8 ----------
__global__ __launch_bounds__(256, 4) void nnue_wave_q8(
    const int*   __restrict__ w_feats,
    const int*   __restrict__ b_feats,
    const int*   __restrict__ stm,
    const int*   __restrict__ bucket,
    const char*  __restrict__ tb,
    const float* __restrict__ ft_bias,
    const float* __restrict__ psqt_w,
    const float* __restrict__ fc0_w,
    const float* __restrict__ fc0_b,
    const float* __restrict__ fc1_w,
    const float* __restrict__ fc1_b,
    const float* __restrict__ fc2_w,
    const float* __restrict__ fc2_b,
    float*       __restrict__ out,
    int nB)
{
    const int tid  = threadIdx.x;
    const int lane = tid & 63;
    const int wv   = tid >> 6;
    const int s    = blockIdx.x * 4 + wv;
    if (s >= nB) return;

    const int* __restrict__ wf = w_feats + s * FEATS;
    const int* __restrict__ bf = b_feats + s * FEATS;
    const size_t loff = (size_t)(lane * 16);

    unsigned accW[8] = {0,0,0,0,0,0,0,0};
    unsigned accB[8] = {0,0,0,0,0,0,0,0};
    {
        uint4 buf[16];
        #pragma unroll
        for (int batch = 0; batch < 4; ++batch) {
            const int* fp = ((batch < 2) ? wf : bf) + (batch & 1) * 16;
            #pragma unroll
            for (int k = 0; k < 16; ++k)
                buf[k] = *reinterpret_cast<const uint4*>(tb + ((size_t)fp[k] << 10) + loff);
            unsigned* acc = (batch < 2) ? accW : accB;
            #pragma unroll
            for (int k = 0; k < 16; ++k) dec16(buf[k], acc);
        }
    }

    const int pj = lane & 7, rg = lane >> 3;
    float psw = 0.0f, psb = 0.0f;
    #pragma unroll
    for (int t = 0; t < 4; ++t) psw += psqt_w[(size_t)wf[t * 8 + rg] * 8 + pj];
    #pragma unroll
    for (int t = 0; t < 4; ++t) psb += psqt_w[(size_t)bf[t * 8 + rg] * 8 + pj];
    psw += __shfl_xor(psw, 8);  psb += __shfl_xor(psb, 8);
    psw += __shfl_xor(psw, 16); psb += __shfl_xor(psb, 16);
    psw += __shfl_xor(psw, 32); psb += __shfl_xor(psb, 32);

    const int st = stm[s];
    unsigned as_[8], ao_[8];
    #pragma unroll
    for (int i = 0; i < 8; ++i) {
        as_[i] = st ? accB[i] : accW[i];
        ao_[i] = st ? accW[i] : accB[i];
    }
    unsigned asw[8], aosw[8];
    #pragma unroll
    for (int i = 0; i < 8; ++i) {
        asw[i]  = __shfl_xor(as_[i], 32);
        aosw[i] = __shfl_xor(ao_[i], 32);
    }
    const bool hiG  = (lane >= 32);
    const int cbase = (lane & 31) * 16;

    const float qs   = QSCALE;
    const float qoff = -4096.0f * QSCALE;
    float ftv[16];
    #pragma unroll
    for (int i2 = 0; i2 < 8; ++i2) {
        const unsigned lo = hiG ? aosw[i2] : as_[i2];
        const unsigned hi = hiG ? ao_[i2]  : asw[i2];
        const float bl0 = ft_bias[cbase + 2 * i2];
        const float bl1 = ft_bias[cbase + 2 * i2 + 1];
        const float bh0 = ft_bias[cbase + HH + 2 * i2];
        const float bh1 = ft_bias[cbase + HH + 2 * i2 + 1];
        const float a0 = (float)(lo & 0xFFFFu) * qs + (bl0 + qoff);
        const float a1 = (float)(lo >> 16)     * qs + (bl1 + qoff);
        const float h0 = (float)(hi & 0xFFFFu) * qs + (bh0 + qoff);
        const float h1 = (float)(hi >> 16)     * qs + (bh1 + qoff);
        ftv[2 * i2]     = clip127(a0) * clip127(h0) * (1.0f / 128.0f);
        ftv[2 * i2 + 1] = clip127(a1) * clip127(h1) * (1.0f / 128.0f);
    }

    const int bk = bucket[s];
    const float* __restrict__ w0 = fc0_w + (size_t)bk * 16 * FTO + 16 * lane;
    float o0[16];
    #pragma unroll
    for (int o = 0; o < 16; ++o) {
        const float4* wr = reinterpret_cast<const float4*>(w0 + o * FTO);
        float pv = 0.0f;
        #pragma unroll
        for (int q = 0; q < 4; ++q) {
            const float4 w = wr[q];
            pv += ftv[4*q] * w.x + ftv[4*q+1] * w.y + ftv[4*q+2] * w.z + ftv[4*q+3] * w.w;
        }
        pv += __shfl_xor(pv, 1);
        pv += __shfl_xor(pv, 2);
        pv += __shfl_xor(pv, 4);
        pv += __shfl_xor(pv, 8);
        pv += __shfl_xor(pv, 16);
        pv += __shfl_xor(pv, 32);
        o0[o] = pv + fc0_b[bk * 16 + o];
    }

    float v = 0.0f;
    if (lane < 32) {
        const float* __restrict__ w1 = fc1_w + ((size_t)bk * 32 + lane) * 32;
        float o1 = fc1_b[bk * 32 + lane];
        #pragma unroll
        for (int i = 0; i < 15; ++i) {
            const float o0i = o0[i];
            const float sq  = clip127(o0i * o0i * (1.0f/524288.0f));
            const float rl  = clip127(o0i * (1.0f/64.0f));
            o1 += sq * w1[i] + rl * w1[15 + i];
        }
        const float ac1 = clip127(o1 * (1.0f/64.0f));
        v = ac1 * fc2_w[bk * 32 + lane];
    }
    v += __shfl_xor(v, 1);
    v += __shfl_xor(v, 2);
    v += __shfl_xor(v, 4);
    v += __shfl_xor(v, 8);
    v += __shfl_xor(v, 16);
    v += __shfl_xor(v, 32);

    const float pwbk = __shfl(psw, bk);
    const float pbbk = __shfl(psb, bk);

    if (lane == 0) {
        const float scalar = v + fc2_b[bk];
        const float skip   = o0[15] * (9600.0f / 8128.0f);
        const float p_stm  = st ? pbbk : pwbk;
        const float p_opp  = st ? pwbk : pbbk;
        out[s] = ((p_stm - p_opp) * 0.5f + scalar + skip) * (1.0f / 16.0f);
    }
}

extern "C" void kernel_launch(void* const* d_in, const int* in_sizes, int n_in,
                              void* d_out, int out_size, void* d_ws, size_t ws_size,
                              hipStream_t stream) {
    const int*   w_feats = (const int*)  d_in[0];
    const int*   b_feats = (const int*)  d_in[2];
    const int*   stm     = (const int*)  d_in[4];
    const int*   bucket  = (const int*)  d_in[5];
    const float* ft_w    = (const float*)d_in[6];
    const float* ft_bias = (const float*)d_in[7];
    const float* psqt_w  = (const float*)d_in[8];
    const float* fc0_w   = (const float*)d_in[9];
    const float* fc0_b   = (const float*)d_in[10];
    const float* fc1_w   = (const float*)d_in[11];
    const float* fc1_b   = (const float*)d_in[12];
    const float* fc2_w   = (const float*)d_in[13];
    const float* fc2_b   = (const float*)d_in[14];
    float* out = (float*)d_out;

    const int nB = in_sizes[4];

    const size_t accf_bytes = (size_t)nB * 8 * 16 * 4;       // 512 B/sample
    const size_t need_shard = FT_ELEMS + accf_bytes + FC0SH_BYTES;

    if (ws_size >= need_shard) {
        char*   tbl_sh = (char*)d_ws;
        float*  acc_f  = (float*)((char*)d_ws + FT_ELEMS);
        __half* fc0sh  = (__half*)((char*)d_ws + FT_ELEMS + accf_bytes);

        prep_all<<<QUANT_BLOCKS + CVT_BLOCKS, 256, 0, stream>>>(
            ft_w, fc0_w, tbl_sh, fc0sh);
        k1_fused<<<8 * ((nB + 31) / 32), 256, 0, stream>>>(
            w_feats, b_feats, stm, bucket, tbl_sh, fc0sh, ft_bias, acc_f, nB);
        k2_final<<<(nB + 3) / 4, 256, 0, stream>>>(
            w_feats, b_feats, stm, bucket, acc_f, psqt_w,
            fc0_b, fc1_w, fc1_b, fc2_w, fc2_b, out, nB);
    } else if (ws_size >= FT_ELEMS) {
        const unsigned n16 = (unsigned)(FT_ELEMS / 16);
        quant_f32_u8<<<2048, 256, 0, stream>>>((const float4*)ft_w, (uint4*)d_ws, n16);
        nnue_wave_q8<<<(nB + 3) / 4, 256, 0, stream>>>(
            w_feats, b_feats, stm, bucket, (const char*)d_ws, ft_bias, psqt_w,
            fc0_w, fc0_b, fc1_w, fc1_b, fc2_w, fc2_b, out, nB);
    }
}

// Round 12
// 66.378 us; speedup vs baseline: 3.8169x; 1.0073x over previous
//
#include <hip/hip_runtime.h>
#include <hip/hip_fp16.h>

// NNUE (HalfKA) fused forward pass for MI355X.
// Round 12: r11 structure; k1 gather register-dieted (batch=4, packed u16
// indices, in-loop biases) to land NATURALLY under the 64-VGPR cliff ->
// 8 waves/SIMD. No forced launch bound (r10 lesson: forcing = spills).

#define FEATS 32
#define FTO   1024
#define HH    512
#define ROWS  22528
#define FT_ELEMS  (22528ULL * 1024ULL)     // int8 table bytes = 23,068,672
#define FC0SH_BYTES (8ULL * 8 * 16 * 128 * 2)  // 262,144
#define QSCALE   (6.0f / 127.0f)
#define QUANT_BLOCKS (8 * (ROWS / 32))     // 5632
#define CVT_BLOCKS   512                   // 131072 / 256

__device__ __forceinline__ float clip127(float x) {
    return fminf(fmaxf(x, 0.0f), 127.0f);
}

__device__ __forceinline__ void dec16(const uint4 v, unsigned* acc) {
    acc[0] += __builtin_amdgcn_perm(v.x, v.x, 0x0C010C00u);
    acc[1] += __builtin_amdgcn_perm(v.x, v.x, 0x0C030C02u);
    acc[2] += __builtin_amdgcn_perm(v.y, v.y, 0x0C010C00u);
    acc[3] += __builtin_amdgcn_perm(v.y, v.y, 0x0C030C02u);
    acc[4] += __builtin_amdgcn_perm(v.z, v.z, 0x0C010C00u);
    acc[5] += __builtin_amdgcn_perm(v.z, v.z, 0x0C030C02u);
    acc[6] += __builtin_amdgcn_perm(v.w, v.w, 0x0C010C00u);
    acc[7] += __builtin_amdgcn_perm(v.w, v.w, 0x0C030C02u);
}

__device__ __forceinline__ void quant16(const float4 a, const float4 b,
                                        const float4 c, const float4 d,
                                        unsigned* w) {
    const float inv = 127.0f / 6.0f;
    const float4 vs[4] = {a, b, c, d};
    #pragma unroll
    for (int j = 0; j < 4; ++j) {
        const float4 v = vs[j];
        const unsigned q0 = (unsigned)(__float2int_rn(fminf(fmaxf(v.x * inv, -127.f), 127.f)) + 128);
        const unsigned q1 = (unsigned)(__float2int_rn(fminf(fmaxf(v.y * inv, -127.f), 127.f)) + 128);
        const unsigned q2 = (unsigned)(__float2int_rn(fminf(fmaxf(v.z * inv, -127.f), 127.f)) + 128);
        const unsigned q3 = (unsigned)(__float2int_rn(fminf(fmaxf(v.w * inv, -127.f), 127.f)) + 128);
        w[j] = q0 | (q1 << 8) | (q2 << 16) | (q3 << 24);
    }
}

// ---------------- prep: table quant (sharded) + fc0 fp16 cvt, one kernel -----
// Blocks [0, 5632): quantize ft_w into pairing-aware shards.
//   shard g row layout (128 B): [0,64)=cols [64g,64g+64),
//                               [64,128)=cols [512+64g,512+64g+64).
// Blocks [5632, 6144): convert fc0_w into sharded fp16 [g][bk][o][j128].
__global__ __launch_bounds__(256) void prep_all(const float* __restrict__ ft_w,
                                                const float* __restrict__ fc0_w,
                                                char* __restrict__ tbl_sh,
                                                __half* __restrict__ fc0h) {
    const int cb = (int)blockIdx.x - QUANT_BLOCKS;
    if (cb < 0) {
        const int g     = blockIdx.x & 7;
        const int chunk = blockIdx.x >> 3;           // [0, 704)
        const int t     = threadIdx.x;
        const int row   = chunk * 32 + (t >> 3);
        const int c16   = (t & 7) * 16;              // byte offset in shard row
        const int col   = (c16 < 64) ? (64 * g + c16) : (512 + 64 * g + (c16 - 64));
        const float4* s4 = reinterpret_cast<const float4*>(
            ft_w + (size_t)row * FTO + col);
        unsigned w[4];
        quant16(s4[0], s4[1], s4[2], s4[3], w);
        *reinterpret_cast<uint4*>(tbl_sh + (size_t)g * (ROWS * 128)
                                  + (size_t)row * 128 + c16) =
            make_uint4(w[0], w[1], w[2], w[3]);
    } else {
        const int idx = cb * 256 + threadIdx.x;      // < 131072
        const int j  = idx & 127;
        const int o  = (idx >> 7) & 15;
        const int bk = (idx >> 11) & 7;
        const int g  = idx >> 14;
        const int col = (j < 64) ? (64 * g + j) : (512 + 64 * g + (j - 64));
        fc0h[idx] = __float2half_rn(fc0_w[((size_t)bk * 16 + o) * FTO + col]);
    }
}

// ---------------- quantize row-major (round-5 fallback) ----------------------
__global__ __launch_bounds__(256) void quant_f32_u8(const float4* __restrict__ src,
                                                    uint4* __restrict__ dst,
                                                    unsigned n16) {
    unsigned i = blockIdx.x * 256 + threadIdx.x;
    const unsigned stride = gridDim.x * 256;
    for (; i < n16; i += stride) {
        unsigned w[4];
        quant16(src[4*(size_t)i], src[4*(size_t)i+1], src[4*(size_t)i+2],
                src[4*(size_t)i+3], w);
        dst[i] = make_uint4(w[0], w[1], w[2], w[3]);
    }
}

// ---------------- K1: transposed sharded gather + pairwise + fc0 -------------
// Block: shard g = blockIdx&7 (XCD heuristic); 4 waves x 8 samples.
// Lane = samp8*8 + c: owns 16B chunk c of shard row for sample samp8.
// Register diet for 8 waves/SIMD: buf[4], pk[4] packed u16 indices,
// biases loaded in-loop. NO forced occupancy bound (r10 lesson).
__global__ __launch_bounds__(256, 4) void k1_fused(
    const int*    __restrict__ w_feats,
    const int*    __restrict__ b_feats,
    const int*    __restrict__ stm,
    const int*    __restrict__ bucket,
    const char*   __restrict__ tbl_sh,
    const __half* __restrict__ fc0_sh,
    const float*  __restrict__ ft_bias,
    float*        __restrict__ acc_f,
    int nB)
{
    const int tid   = threadIdx.x;
    const int lane  = tid & 63;
    const int wv    = tid >> 6;
    const int g     = blockIdx.x & 7;
    const int slot  = (blockIdx.x >> 3) * 4 + wv;
    const int samp8 = lane >> 3;
    const int c     = lane & 7;
    const int s0    = slot * 8 + samp8;
    const int s     = (s0 < nB) ? s0 : (nB - 1);
    const size_t gbase = (size_t)g * (ROWS * 128ULL);
    const char* __restrict__ tbc = tbl_sh + gbase + c * 16;

    // ---- packed indices: pk[j] = pos(2j) | pos(2j+1)<<16 (rows < 2^15) ----
    // il[q] := feats[c + 8q] (q<4: w-bag, q>=4: b-bag); pk[j] = il[2j]|il[2j+1]<<16
    int pk[4];
    {
        const int* __restrict__ wf = w_feats + (size_t)s * FEATS;
        const int* __restrict__ bf = b_feats + (size_t)s * FEATS;
        pk[0] = wf[c]      | (wf[c + 8]  << 16);
        pk[1] = wf[c + 16] | (wf[c + 24] << 16);
        pk[2] = bf[c]      | (bf[c + 8]  << 16);
        pk[3] = bf[c + 16] | (bf[c + 24] << 16);
    }

    // ---- gather-sum: 16 batches of 4 row-chunk loads ----
    unsigned accW[8] = {0,0,0,0,0,0,0,0};
    unsigned accB[8] = {0,0,0,0,0,0,0,0};
    const int grpbase = lane & 56;
    #pragma unroll
    for (int t = 0; t < 16; ++t) {
        const int q = t >> 1;                 // il index (0..7)
        uint4 buf[4];
        #pragma unroll
        for (int u = 0; u < 4; ++u) {
            const int pr  = __shfl(pk[q >> 1], grpbase + (t & 1) * 4 + u);
            const int row = (q & 1) ? (pr >> 16) : (pr & 0xFFFF);
            buf[u] = *reinterpret_cast<const uint4*>(tbc + (size_t)row * 128);
        }
        unsigned* acc = (t < 8) ? accW : accB;
        #pragma unroll
        for (int u = 0; u < 4; ++u) dec16(buf[u], acc);
    }

    const int st = stm[s];
    const int bk = bucket[s];

    // ---- stm select + pairing exchange with lane c^4 ----
    unsigned A[8], P[8];
    #pragma unroll
    for (int i = 0; i < 8; ++i) {
        const unsigned sS = st ? accB[i] : accW[i];
        const unsigned sO = st ? accW[i] : accB[i];
        A[i] = (c < 4) ? sS : sO;
        P[i] = __shfl_xor((c < 4) ? sO : sS, 4);
    }

    // ---- decode + pairwise clip-mult (biases loaded in-loop, L1-hot) ----
    const float qs   = QSCALE;
    const float qoff = -4096.0f * QSCALE;   // 32 rows * 128 bias
    const int cbo      = 16 * (c & 3);
    const int lo_base  = 64 * g + cbo;
    const int hi_base  = 512 + 64 * g + cbo;
    const int own_base = (c < 4) ? lo_base : hi_base;
    const int par_base = (c < 4) ? hi_base : lo_base;

    float ftv[16];
    #pragma unroll
    for (int i2 = 0; i2 < 4; ++i2) {
        const float4 vo = *reinterpret_cast<const float4*>(ft_bias + own_base + 4 * i2);
        const float4 vp = *reinterpret_cast<const float4*>(ft_bias + par_base + 4 * i2);
        const unsigned a0 = A[2 * i2], a1 = A[2 * i2 + 1];
        const unsigned p0 = P[2 * i2], p1 = P[2 * i2 + 1];
        const float o0v = (float)(a0 & 0xFFFFu) * qs + (vo.x + qoff);
        const float o1v = (float)(a0 >> 16)     * qs + (vo.y + qoff);
        const float o2v = (float)(a1 & 0xFFFFu) * qs + (vo.z + qoff);
        const float o3v = (float)(a1 >> 16)     * qs + (vo.w + qoff);
        const float q0v = (float)(p0 & 0xFFFFu) * qs + (vp.x + qoff);
        const float q1v = (float)(p0 >> 16)     * qs + (vp.y + qoff);
        const float q2v = (float)(p1 & 0xFFFFu) * qs + (vp.z + qoff);
        const float q3v = (float)(p1 >> 16)     * qs + (vp.w + qoff);
        ftv[4*i2+0] = clip127(o0v) * clip127(q0v) * (1.0f/128.0f);
        ftv[4*i2+1] = clip127(o1v) * clip127(q1v) * (1.0f/128.0f);
        ftv[4*i2+2] = clip127(o2v) * clip127(q2v) * (1.0f/128.0f);
        ftv[4*i2+3] = clip127(o3v) * clip127(q3v) * (1.0f/128.0f);
    }

    // ---- fc0 partials from L1-hot global weights (32 KB/shard) ----
    const __half* __restrict__ wbase =
        fc0_sh + ((size_t)g * 8 + bk) * (16 * 128) + 16 * c;
    float p[16];
    #pragma unroll
    for (int o = 0; o < 16; ++o) {
        const __half2* w2 = reinterpret_cast<const __half2*>(wbase + o * 128);
        float pv = 0.0f;
        #pragma unroll
        for (int j = 0; j < 8; ++j) {
            const float2 f = __half22float2(w2[j]);
            pv += ftv[2*j] * f.x + ftv[2*j+1] * f.y;
        }
        p[o] = pv;
    }

    // ---- 14-shuffle keep/send tree: 16 partials over 8 lanes -> 2/lane ----
    float q8[8];
    {
        const bool hi = (c & 1) != 0;
        #pragma unroll
        for (int o = 0; o < 8; ++o) {
            const float send = hi ? p[o] : p[o + 8];
            const float keep = hi ? p[o + 8] : p[o];
            q8[o] = keep + __shfl_xor(send, 1);
        }
    }
    float q4[4];
    {
        const bool hi = (c & 2) != 0;
        #pragma unroll
        for (int o = 0; o < 4; ++o) {
            const float send = hi ? q8[o] : q8[o + 4];
            const float keep = hi ? q8[o + 4] : q8[o];
            q4[o] = keep + __shfl_xor(send, 2);
        }
    }
    float q2[2];
    {
        const bool hi = (c & 4) != 0;
        #pragma unroll
        for (int o = 0; o < 2; ++o) {
            const float send = hi ? q4[o] : q4[o + 2];
            const float keep = hi ? q4[o + 2] : q4[o];
            q2[o] = keep + __shfl_xor(send, 4);
        }
    }
    // lane c holds outs {2m, 2m+1}, m = bit-reversed c (3 bits)
    const int m = ((c & 1) << 2) | (c & 2) | (c >> 2);

    if (s0 < nB) {
        float2* dst = reinterpret_cast<float2*>(acc_f + ((size_t)s * 8 + g) * 16);
        dst[m] = make_float2(q2[0], q2[1]);
    }
}

// ---------------- K2: tiny finisher ----------------
__global__ __launch_bounds__(256, 4) void k2_final(
    const int*   __restrict__ w_feats,
    const int*   __restrict__ b_feats,
    const int*   __restrict__ stm,
    const int*   __restrict__ bucket,
    const float* __restrict__ acc_f,
    const float* __restrict__ psqt_w,
    const float* __restrict__ fc0_b,
    const float* __restrict__ fc1_w,
    const float* __restrict__ fc1_b,
    const float* __restrict__ fc2_w,
    const float* __restrict__ fc2_b,
    float*       __restrict__ out,
    int nB)
{
    const int tid  = threadIdx.x;
    const int lane = tid & 63;
    const int wv   = tid >> 6;
    const int s    = blockIdx.x * 4 + wv;
    if (s >= nB) return;

    const int* __restrict__ wf = w_feats + s * FEATS;
    const int* __restrict__ bf = b_feats + s * FEATS;

    // ---- psqt gather ----
    const int pj = lane & 7, rg = lane >> 3;
    float psw = 0.0f, psb = 0.0f;
    #pragma unroll
    for (int t = 0; t < 4; ++t) psw += psqt_w[(size_t)wf[t * 8 + rg] * 8 + pj];
    #pragma unroll
    for (int t = 0; t < 4; ++t) psb += psqt_w[(size_t)bf[t * 8 + rg] * 8 + pj];
    psw += __shfl_xor(psw, 8);  psb += __shfl_xor(psb, 8);
    psw += __shfl_xor(psw, 16); psb += __shfl_xor(psb, 16);
    psw += __shfl_xor(psw, 32); psb += __shfl_xor(psb, 32);

    const int st = stm[s];
    const int bk = bucket[s];

    // ---- o0: sum 8 shard partials; lane holds o = lane&15 ----
    const float r0 = acc_f[(size_t)s * 128 + lane];        // g = lane>>4
    const float r1 = acc_f[(size_t)s * 128 + 64 + lane];   // g = 4 + (lane>>4)
    float v = r0 + r1;
    v += __shfl_xor(v, 16);
    v += __shfl_xor(v, 32);
    v += fc0_b[bk * 16 + (lane & 15)];

    // ---- fc1 on lanes 0..31 ----
    float t2 = 0.0f;
    if (lane < 32) {
        const float* __restrict__ w1 = fc1_w + ((size_t)bk * 32 + lane) * 32;
        float o1 = fc1_b[bk * 32 + lane];
        #pragma unroll
        for (int i = 0; i < 15; ++i) {
            const float o0i = __shfl(v, i);
            const float sq  = clip127(o0i * o0i * (1.0f/524288.0f));
            const float rl  = clip127(o0i * (1.0f/64.0f));
            o1 += sq * w1[i] + rl * w1[15 + i];
        }
        const float ac1 = clip127(o1 * (1.0f/64.0f));
        t2 = ac1 * fc2_w[bk * 32 + lane];
    } else {
        (void)__shfl(v, 0);
    }
    t2 += __shfl_xor(t2, 1);
    t2 += __shfl_xor(t2, 2);
    t2 += __shfl_xor(t2, 4);
    t2 += __shfl_xor(t2, 8);
    t2 += __shfl_xor(t2, 16);
    t2 += __shfl_xor(t2, 32);

    const float skip = __shfl(v, 15) * (9600.0f / 8128.0f);
    const float pwbk = __shfl(psw, bk);
    const float pbbk = __shfl(psb, bk);

    if (lane == 0) {
        const float scalar = t2 + fc2_b[bk];
        const float p_stm  = st ? pbbk : pwbk;
        const float p_opp  = st ? pwbk : pbbk;
        out[s] = ((p_stm - p_opp) * 0.5f + scalar + skip) * (1.0f / 16.0f);
    }
}

// ---------------- round-5 fallback: wave-per-sample, row-major int8 ----------
__global__ __launch_bounds__(256, 4) void nnue_wave_q8(
    const int*   __restrict__ w_feats,
    const int*   __restrict__ b_feats,
    const int*   __restrict__ stm,
    const int*   __restrict__ bucket,
    const char*  __restrict__ tb,
    const float* __restrict__ ft_bias,
    const float* __restrict__ psqt_w,
    const float* __restrict__ fc0_w,
    const float* __restrict__ fc0_b,
    const float* __restrict__ fc1_w,
    const float* __restrict__ fc1_b,
    const float* __restrict__ fc2_w,
    const float* __restrict__ fc2_b,
    float*       __restrict__ out,
    int nB)
{
    const int tid  = threadIdx.x;
    const int lane = tid & 63;
    const int wv   = tid >> 6;
    const int s    = blockIdx.x * 4 + wv;
    if (s >= nB) return;

    const int* __restrict__ wf = w_feats + s * FEATS;
    const int* __restrict__ bf = b_feats + s * FEATS;
    const size_t loff = (size_t)(lane * 16);

    unsigned accW[8] = {0,0,0,0,0,0,0,0};
    unsigned accB[8] = {0,0,0,0,0,0,0,0};
    {
        uint4 buf[16];
        #pragma unroll
        for (int batch = 0; batch < 4; ++batch) {
            const int* fp = ((batch < 2) ? wf : bf) + (batch & 1) * 16;
            #pragma unroll
            for (int k = 0; k < 16; ++k)
                buf[k] = *reinterpret_cast<const uint4*>(tb + ((size_t)fp[k] << 10) + loff);
            unsigned* acc = (batch < 2) ? accW : accB;
            #pragma unroll
            for (int k = 0; k < 16; ++k) dec16(buf[k], acc);
        }
    }

    const int pj = lane & 7, rg = lane >> 3;
    float psw = 0.0f, psb = 0.0f;
    #pragma unroll
    for (int t = 0; t < 4; ++t) psw += psqt_w[(size_t)wf[t * 8 + rg] * 8 + pj];
    #pragma unroll
    for (int t = 0; t < 4; ++t) psb += psqt_w[(size_t)bf[t * 8 + rg] * 8 + pj];
    psw += __shfl_xor(psw, 8);  psb += __shfl_xor(psb, 8);
    psw += __shfl_xor(psw, 16); psb += __shfl_xor(psb, 16);
    psw += __shfl_xor(psw, 32); psb += __shfl_xor(psb, 32);

    const int st = stm[s];
    unsigned as_[8], ao_[8];
    #pragma unroll
    for (int i = 0; i < 8; ++i) {
        as_[i] = st ? accB[i] : accW[i];
        ao_[i] = st ? accW[i] : accB[i];
    }
    unsigned asw[8], aosw[8];
    #pragma unroll
    for (int i = 0; i < 8; ++i) {
        asw[i]  = __shfl_xor(as_[i], 32);
        aosw[i] = __shfl_xor(ao_[i], 32);
    }
    const bool hiG  = (lane >= 32);
    const int cbase = (lane & 31) * 16;

    const float qs   = QSCALE;
    const float qoff = -4096.0f * QSCALE;
    float ftv[16];
    #pragma unroll
    for (int i2 = 0; i2 < 8; ++i2) {
        const unsigned lo = hiG ? aosw[i2] : as_[i2];
        const unsigned hi = hiG ? ao_[i2]  : asw[i2];
        const float bl0 = ft_bias[cbase + 2 * i2];
        const float bl1 = ft_bias[cbase + 2 * i2 + 1];
        const float bh0 = ft_bias[cbase + HH + 2 * i2];
        const float bh1 = ft_bias[cbase + HH + 2 * i2 + 1];
        const float a0 = (float)(lo & 0xFFFFu) * qs + (bl0 + qoff);
        const float a1 = (float)(lo >> 16)     * qs + (bl1 + qoff);
        const float h0 = (float)(hi & 0xFFFFu) * qs + (bh0 + qoff);
        const float h1 = (float)(hi >> 16)     * qs + (bh1 + qoff);
        ftv[2 * i2]     = clip127(a0) * clip127(h0) * (1.0f / 128.0f);
        ftv[2 * i2 + 1] = clip127(a1) * clip127(h1) * (1.0f / 128.0f);
    }

    const int bk = bucket[s];
    const float* __restrict__ w0 = fc0_w + (size_t)bk * 16 * FTO + 16 * lane;
    float o0[16];
    #pragma unroll
    for (int o = 0; o < 16; ++o) {
        const float4* wr = reinterpret_cast<const float4*>(w0 + o * FTO);
        float pv = 0.0f;
        #pragma unroll
        for (int q = 0; q < 4; ++q) {
            const float4 w = wr[q];
            pv += ftv[4*q] * w.x + ftv[4*q+1] * w.y + ftv[4*q+2] * w.z + ftv[4*q+3] * w.w;
        }
        pv += __shfl_xor(pv, 1);
        pv += __shfl_xor(pv, 2);
        pv += __shfl_xor(pv, 4);
        pv += __shfl_xor(pv, 8);
        pv += __shfl_xor(pv, 16);
        pv += __shfl_xor(pv, 32);
        o0[o] = pv + fc0_b[bk * 16 + o];
    }

    float v = 0.0f;
    if (lane < 32) {
        const float* __restrict__ w1 = fc1_w + ((size_t)bk * 32 + lane) * 32;
        float o1 = fc1_b[bk * 32 + lane];
        #pragma unroll
        for (int i = 0; i < 15; ++i) {
            const float o0i = o0[i];
            const float sq  = clip127(o0i * o0i * (1.0f/524288.0f));
            const float rl  = clip127(o0i * (1.0f/64.0f));
            o1 += sq * w1[i] + rl * w1[15 + i];
        }
        const float ac1 = clip127(o1 * (1.0f/64.0f));
        v = ac1 * fc2_w[bk * 32 + lane];
    }
    v += __shfl_xor(v, 1);
    v += __shfl_xor(v, 2);
    v += __shfl_xor(v, 4);
    v += __shfl_xor(v, 8);
    v += __shfl_xor(v, 16);
    v += __shfl_xor(v, 32);

    const float pwbk = __shfl(psw, bk);
    const float pbbk = __shfl(psb, bk);

    if (lane == 0) {
        const float scalar = v + fc2_b[bk];
        const float skip   = o0[15] * (9600.0f / 8128.0f);
        const float p_stm  = st ? pbbk : pwbk;
        const float p_opp  = st ? pwbk : pbbk;
        out[s] = ((p_stm - p_opp) * 0.5f + scalar + skip) * (1.0f / 16.0f);
    }
}

extern "C" void kernel_launch(void* const* d_in, const int* in_sizes, int n_in,
                              void* d_out, int out_size, void* d_ws, size_t ws_size,
                              hipStream_t stream) {
    const int*   w_feats = (const int*)  d_in[0];
    const int*   b_feats = (const int*)  d_in[2];
    const int*   stm     = (const int*)  d_in[4];
    const int*   bucket  = (const int*)  d_in[5];
    const float* ft_w    = (const float*)d_in[6];
    const float* ft_bias = (const float*)d_in[7];
    const float* psqt_w  = (const float*)d_in[8];
    const float* fc0_w   = (const float*)d_in[9];
    const float* fc0_b   = (const float*)d_in[10];
    const float* fc1_w   = (const float*)d_in[11];
    const float* fc1_b   = (const float*)d_in[12];
    const float* fc2_w   = (const float*)d_in[13];
    const float* fc2_b   = (const float*)d_in[14];
    float* out = (float*)d_out;

    const int nB = in_sizes[4];

    const size_t accf_bytes = (size_t)nB * 8 * 16 * 4;       // 512 B/sample
    const size_t need_shard = FT_ELEMS + accf_bytes + FC0SH_BYTES;

    if (ws_size >= need_shard) {
        char*   tbl_sh = (char*)d_ws;
        float*  acc_f  = (float*)((char*)d_ws + FT_ELEMS);
        __half* fc0sh  = (__half*)((char*)d_ws + FT_ELEMS + accf_bytes);

        prep_all<<<QUANT_BLOCKS + CVT_BLOCKS, 256, 0, stream>>>(
            ft_w, fc0_w, tbl_sh, fc0sh);
        k1_fused<<<8 * ((nB + 31) / 32), 256, 0, stream>>>(
            w_feats, b_feats, stm, bucket, tbl_sh, fc0sh, ft_bias, acc_f, nB);
        k2_final<<<(nB + 3) / 4, 256, 0, stream>>>(
            w_feats, b_feats, stm, bucket, acc_f, psqt_w,
            fc0_b, fc1_w, fc1_b, fc2_w, fc2_b, out, nB);
    } else if (ws_size >= FT_ELEMS) {
        const unsigned n16 = (unsigned)(FT_ELEMS / 16);
        quant_f32_u8<<<2048, 256, 0, stream>>>((const float4*)ft_w, (uint4*)d_ws, n16);
        nnue_wave_q8<<<(nB + 3) / 4, 256, 0, stream>>>(
            w_feats, b_feats, stm, bucket, (const char*)d_ws, ft_bias, psqt_w,
            fc0_w, fc0_b, fc1_w, fc1_b, fc2_w, fc2_b, out, nB);
    }
}